// Round 5
// baseline (2842.356 us; speedup 1.0000x reference)
//
#include <hip/hip_runtime.h>
#include <hip/hip_bf16.h>
#include <cstdint>
#include <cstddef>

#define B_ 128
#define T_ 1024
#define D_ 256
#define U_ 256

typedef __bf16 bfrag __attribute__((ext_vector_type(8)));
typedef unsigned short us8 __attribute__((ext_vector_type(8)));
typedef unsigned short us4 __attribute__((ext_vector_type(4)));
typedef float f32x4 __attribute__((ext_vector_type(4)));

__device__ __forceinline__ unsigned short f2bf(float f) {
    unsigned int u = __builtin_bit_cast(unsigned int, f);
    unsigned int r = (u + 0x7fffu + ((u >> 16) & 1u)) >> 16;
    return (unsigned short)r;
}
__device__ __forceinline__ float bf2f(unsigned short h) {
    unsigned int u = ((unsigned int)h) << 16;
    return __builtin_bit_cast(float, u);
}
// HW packed f32->2xbf16 (RNE). Used ONLY in wt/proj (one-shot kernels);
// in gru_rec's hot loop the inline asm perturbed scheduling (R3 regression).
__device__ __forceinline__ unsigned int pk_bf16(float lo, float hi) {
    unsigned int d;
    asm("v_cvt_pk_bf16_f32 %0, %1, %2" : "=v"(d) : "v"(lo), "v"(hi));
    return d;
}

#if __has_builtin(__builtin_amdgcn_exp2f)
__device__ __forceinline__ float fexp2(float x) { return __builtin_amdgcn_exp2f(x); }
#else
__device__ __forceinline__ float fexp2(float x) { return exp2f(x); }
#endif
#if __has_builtin(__builtin_amdgcn_rcpf)
__device__ __forceinline__ float frcp(float x) { return __builtin_amdgcn_rcpf(x); }
#else
__device__ __forceinline__ float frcp(float x) { return 1.0f / x; }
#endif

__device__ __forceinline__ float sigm(float x) {
    return frcp(1.0f + fexp2(-1.4426950408889634f * x));
}
__device__ __forceinline__ float tanh_(float x) {
    return 1.0f - 2.0f * frcp(1.0f + fexp2(2.8853900817779268f * x));
}

// lgkm-only barrier: LDS writes visible, in-flight global loads NOT drained
#define BARRIER_LGKM() asm volatile("s_waitcnt lgkmcnt(0)\n\ts_barrier" ::: "memory")

// sched_group_barrier masks: 0x8=MFMA, 0x20=VMEM read, 0x100=DS read
#if __has_builtin(__builtin_amdgcn_sched_group_barrier)
#define SGB(m, n) __builtin_amdgcn_sched_group_barrier((m), (n), 0)
#else
#define SGB(m, n)
#endif

// xzh layout: [t][g(8)][col(768)][b_local(16)] bf16. col<512: xz+b_zr; col>=512: xh+b_h
#define TSTR (8 * 768 * 16)  // shorts per timestep

// ---------------------------------------------------------------------------
// wt_kernel: Wt[col(768)][k(256)] bf16 = transpose of [W_zr | W_h]
// ---------------------------------------------------------------------------
__global__ __launch_bounds__(64) void wt_kernel(
    const float* __restrict__ Wzr, const float* __restrict__ Wh,
    unsigned short* __restrict__ Wt)
{
    const int c = blockIdx.x;      // 0..767
    const int lane = threadIdx.x;  // 0..63
    const float* Wp; int ldw, cc;
    if (c < 512) { Wp = Wzr; ldw = 512; cc = c; }
    else         { Wp = Wh;  ldw = 256; cc = c - 512; }
    const int k0 = lane * 4;
    const float a = Wp[(size_t)(k0 + 0) * ldw + cc];
    const float b = Wp[(size_t)(k0 + 1) * ldw + cc];
    const float d = Wp[(size_t)(k0 + 2) * ldw + cc];
    const float e = Wp[(size_t)(k0 + 3) * ldw + cc];
    uint2 u; u.x = pk_bf16(a, b); u.y = pk_bf16(d, e);
    *reinterpret_cast<uint2*>(&Wt[(size_t)c * 256 + k0]) = u;
}

// ---------------------------------------------------------------------------
// proj: xzh = x @ [W_zr | W_h] + bias, bf16 out.
// Block 256 thr / 4 waves, BM=64 (16 b x 4 t), N=768 in 12 chunks of 64,
// K=256. A staged to LDS coalesced; A-frags in regs. W read directly from
// L2-resident Wt via per-lane b128 loads in exact MFMA B-fragment layout.
// NEW: sched_group_barrier interleaves W-loads with MFMAs inside each chunk
// so L2 latency hides under the matrix pipe.
// ---------------------------------------------------------------------------
#define LPA 264  // ldsA row pad (shorts): 528 B rows, 16-B aligned

__global__ __launch_bounds__(256, 2) void proj_kernel(
    const float* __restrict__ x, const unsigned short* __restrict__ Wt,
    const float* __restrict__ bzr, const float* __restrict__ bh,
    unsigned short* __restrict__ xzh)
{
    const int tid  = threadIdx.x;
    const int lane = tid & 63;
    const int wv   = tid >> 6;
    const int q    = lane >> 4;
    const int c16  = lane & 15;
    const int bb = blockIdx.x >> 8;   // batch block (16 b)
    const int tb = blockIdx.x & 255;  // time block (4 t)

    __shared__ __align__(16) unsigned short ldsA[64 * LPA];

    // ---- stage A (64 rows x 256 k), coalesced: one full row per instr ----
    {
        const int r0 = wv * 16;
#pragma unroll
        for (int r = 0; r < 16; ++r) {
            const int row = r0 + r;
            const float* xr = x + (((size_t)(bb * 16 + (row & 15))) * T_
                                   + tb * 4 + (row >> 4)) * D_;
            f32x4 v = *reinterpret_cast<const f32x4*>(xr + lane * 4);
            uint2 u; u.x = pk_bf16(v[0], v[1]); u.y = pk_bf16(v[2], v[3]);
            *reinterpret_cast<uint2*>(&ldsA[row * LPA + lane * 4]) = u;
        }
    }
    __syncthreads();

    // ---- A fragments to regs: rows (wv>>1)*32 + m2*16 + c16 ----
    const int R0 = (wv >> 1) * 32;
    us8 af[2][8];
#pragma unroll
    for (int m2 = 0; m2 < 2; ++m2)
#pragma unroll
        for (int kk = 0; kk < 8; ++kk)
            af[m2][kk] = *reinterpret_cast<const us8*>(
                &ldsA[(R0 + m2 * 16 + c16) * LPA + kk * 32 + q * 8]);

    const int wn = wv & 1;
    const unsigned short* p0 = Wt + ((size_t)(wn * 32 + c16) * 256 + q * 8);
    const unsigned short* p1 = p0 + 16 * 256;

#pragma unroll 1
    for (int ch = 0; ch < 12; ++ch) {
        f32x4 acc[2][2] = {};
#pragma unroll
        for (int kk = 0; kk < 8; ++kk) {
            us8 w0 = *reinterpret_cast<const us8*>(p0 + kk * 32);
            us8 w1 = *reinterpret_cast<const us8*>(p1 + kk * 32);
#pragma unroll
            for (int m2 = 0; m2 < 2; ++m2) {
                acc[m2][0] = __builtin_amdgcn_mfma_f32_16x16x32_bf16(
                    __builtin_bit_cast(bfrag, af[m2][kk]), __builtin_bit_cast(bfrag, w0),
                    acc[m2][0], 0, 0, 0);
                acc[m2][1] = __builtin_amdgcn_mfma_f32_16x16x32_bf16(
                    __builtin_bit_cast(bfrag, af[m2][kk]), __builtin_bit_cast(bfrag, w1),
                    acc[m2][1], 0, 0, 0);
            }
        }
        // shape the schedule: 4-load head start, then 4 MFMA : 2 loads
        SGB(0x20, 4);
        SGB(0x8, 4); SGB(0x20, 2);
        SGB(0x8, 4); SGB(0x20, 2);
        SGB(0x8, 4); SGB(0x20, 2);
        SGB(0x8, 4); SGB(0x20, 2);
        SGB(0x8, 4); SGB(0x20, 2);
        SGB(0x8, 4); SGB(0x20, 2);
        SGB(0x8, 8);
#pragma unroll
        for (int n2 = 0; n2 < 2; ++n2) {
            const int gcn = ch * 64 + wn * 32 + n2 * 16 + c16;
            const float bias = (gcn < 512) ? bzr[gcn] : bh[gcn - 512];
#pragma unroll
            for (int m2 = 0; m2 < 2; ++m2) {
                const int t = tb * 4 + (wv >> 1) * 2 + m2;
                uint2 uu;
                uu.x = pk_bf16(acc[m2][n2][0] + bias, acc[m2][n2][1] + bias);
                uu.y = pk_bf16(acc[m2][n2][2] + bias, acc[m2][n2][3] + bias);
                *reinterpret_cast<uint2*>(
                    &xzh[(((size_t)t * 8 + bb) * 768 + gcn) * 16 + q * 4]) = uu;
            }
        }
        p0 += 64 * 256; p1 += 64 * 256;
    }
}

// ---------------------------------------------------------------------------
// gru_rec: R4 structure (proven 1870 us) + sched_group_barrier interleaving
// of DS-reads with MFMAs in both phases (kills the phase-front LDS burst
// that serialized before the MFMA drain). Everything else byte-identical.
// ---------------------------------------------------------------------------
#define HBP 264  // shorts per row

__global__ __launch_bounds__(512, 2) void gru_rec(
    const float* __restrict__ Uzr, const float* __restrict__ Uh,
    const unsigned short* __restrict__ xzh, float* __restrict__ out)
{
    const int tid  = threadIdx.x;
    const int lane = tid & 63;
    const int w    = tid >> 6;
    const int q    = lane >> 4;
    const int c16  = lane & 15;
    const int g    = blockIdx.x;

    __shared__ __align__(16) unsigned short hb[16 * HBP];
    __shared__ __align__(16) unsigned short rhb[16 * HBP];

    // weight preload, k-perm: position p=kk*32+q*8+j holds h-row
    // kr = kk*32 + q*4 + (j>>1) + 16*(j&1)
    us8 wA[4][8];
#pragma unroll
    for (int nt = 0; nt < 4; ++nt) {
        const int col = (nt < 2) ? (w * 32 + nt * 16 + c16)
                                 : (256 + w * 32 + (nt - 2) * 16 + c16);
#pragma unroll
        for (int kk = 0; kk < 8; ++kk) {
            us8 v;
#pragma unroll
            for (int j = 0; j < 8; ++j) {
                const int kr = kk * 32 + q * 4 + (j >> 1) + 16 * (j & 1);
                v[j] = f2bf(Uzr[(size_t)kr * 512 + col]);
            }
            wA[nt][kk] = v;
        }
    }
    us8 wB[2][8];
#pragma unroll
    for (int nt = 0; nt < 2; ++nt) {
        const int col = w * 32 + nt * 16 + c16;
#pragma unroll
        for (int kk = 0; kk < 8; ++kk) {
            us8 v;
#pragma unroll
            for (int j = 0; j < 8; ++j) {
                const int kr = kk * 32 + q * 4 + (j >> 1) + 16 * (j & 1);
                v[j] = f2bf(Uh[(size_t)kr * 256 + col]);
            }
            wB[nt][kk] = v;
        }
    }

    for (int i = tid; i < 16 * HBP; i += 512) { hb[i] = 0; rhb[i] = 0; }
    __syncthreads();

    float hreg[2][4] = {{0, 0, 0, 0}, {0, 0, 0, 0}};

    // per-lane xzh base offsets (shorts)
    size_t laneA[4], laneB[2];
#pragma unroll
    for (int nt = 0; nt < 4; ++nt) {
        const int col = (nt < 2) ? (w * 32 + nt * 16 + c16)
                                 : (256 + w * 32 + (nt - 2) * 16 + c16);
        laneA[nt] = ((size_t)g * 768 + col) * 16 + q * 4;
    }
#pragma unroll
    for (int nt = 0; nt < 2; ++nt)
        laneB[nt] = ((size_t)g * 768 + 512 + w * 32 + nt * 16 + c16) * 16 + q * 4;

    // prefetch t=0
    us4 ca[4], cxh[2];
#pragma unroll
    for (int nt = 0; nt < 4; ++nt)
        ca[nt] = *reinterpret_cast<const us4*>(&xzh[laneA[nt]]);
#pragma unroll
    for (int nt = 0; nt < 2; ++nt)
        cxh[nt] = *reinterpret_cast<const us4*>(&xzh[laneB[nt]]);

    size_t toff = TSTR;  // points at t+1 data

    const int dwi = w * 32 + 2 * c16;  // packed-dword short index within row

#pragma unroll 1
    for (int t = 0; t < T_; ++t) {
        // issue next step's prefetch (lands any time before end of step)
        us4 na[4], nxh[2];
#pragma unroll
        for (int nt = 0; nt < 4; ++nt)
            na[nt] = *reinterpret_cast<const us4*>(&xzh[laneA[nt] + toff]);
#pragma unroll
        for (int nt = 0; nt < 2; ++nt)
            nxh[nt] = *reinterpret_cast<const us4*>(&xzh[laneB[nt] + toff]);
        if (t < 1022) toff += TSTR;

        // ---- phase A: z = xz + h @ U_zr ----
        f32x4 acc[4];
#pragma unroll
        for (int nt = 0; nt < 4; ++nt) {
            acc[nt][0] = bf2f(ca[nt][0]); acc[nt][1] = bf2f(ca[nt][1]);
            acc[nt][2] = bf2f(ca[nt][2]); acc[nt][3] = bf2f(ca[nt][3]);
        }
#pragma unroll
        for (int kk = 0; kk < 8; ++kk) {
            bfrag af = __builtin_bit_cast(bfrag,
                *reinterpret_cast<const us8*>(&hb[c16 * HBP + kk * 32 + q * 8]));
#pragma unroll
            for (int nt = 0; nt < 4; ++nt)
                acc[nt] = __builtin_amdgcn_mfma_f32_16x16x32_bf16(
                    af, __builtin_bit_cast(bfrag, wA[nt][kk]), acc[nt], 0, 0, 0);
        }
        // schedule shape: prefetch VMEM first, 2 DS head start, then 4 MFMA : 1 DS
        SGB(0x20, 6);
        SGB(0x100, 2);
        SGB(0x8, 4); SGB(0x100, 1);
        SGB(0x8, 4); SGB(0x100, 1);
        SGB(0x8, 4); SGB(0x100, 1);
        SGB(0x8, 4); SGB(0x100, 1);
        SGB(0x8, 4); SGB(0x100, 1);
        SGB(0x8, 4); SGB(0x100, 1);
        SGB(0x8, 8);
        // Z stays in regs; R -> R*h -> rhb (packed dword)
        float zreg[2][4];
#pragma unroll
        for (int i = 0; i < 4; ++i) {
            zreg[0][i] = sigm(acc[0][i]);
            zreg[1][i] = sigm(acc[1][i]);
            const float r0 = sigm(acc[2][i]);
            const float r1 = sigm(acc[3][i]);
            const unsigned int pk = (unsigned int)f2bf(r0 * hreg[0][i]) |
                                    ((unsigned int)f2bf(r1 * hreg[1][i]) << 16);
            *reinterpret_cast<unsigned int*>(&rhb[(q * 4 + i) * HBP + dwi]) = pk;
        }
        BARRIER_LGKM();

        // ---- phase B: s = tanh(xh + (R*h) @ U_h); h update ----
        f32x4 acc2[2];
#pragma unroll
        for (int nt = 0; nt < 2; ++nt) {
            acc2[nt][0] = bf2f(cxh[nt][0]); acc2[nt][1] = bf2f(cxh[nt][1]);
            acc2[nt][2] = bf2f(cxh[nt][2]); acc2[nt][3] = bf2f(cxh[nt][3]);
        }
#pragma unroll
        for (int kk = 0; kk < 8; ++kk) {
            bfrag rf = __builtin_bit_cast(bfrag,
                *reinterpret_cast<const us8*>(&rhb[c16 * HBP + kk * 32 + q * 8]));
#pragma unroll
            for (int nt = 0; nt < 2; ++nt)
                acc2[nt] = __builtin_amdgcn_mfma_f32_16x16x32_bf16(
                    rf, __builtin_bit_cast(bfrag, wB[nt][kk]), acc2[nt], 0, 0, 0);
        }
        // schedule shape: 2 DS head start, then 2 MFMA : 1 DS
        SGB(0x100, 2);
        SGB(0x8, 2); SGB(0x100, 1);
        SGB(0x8, 2); SGB(0x100, 1);
        SGB(0x8, 2); SGB(0x100, 1);
        SGB(0x8, 2); SGB(0x100, 1);
        SGB(0x8, 2); SGB(0x100, 1);
        SGB(0x8, 2); SGB(0x100, 1);
        SGB(0x8, 2);
#pragma unroll
        for (int i = 0; i < 4; ++i) {
            const float s0 = tanh_(acc2[0][i]);
            const float s1 = tanh_(acc2[1][i]);
            const float h0 = hreg[0][i] + zreg[0][i] * (s0 - hreg[0][i]);
            const float h1 = hreg[1][i] + zreg[1][i] * (s1 - hreg[1][i]);
            hreg[0][i] = h0; hreg[1][i] = h1;
            const unsigned int pk = (unsigned int)f2bf(h0) |
                                    ((unsigned int)f2bf(h1) << 16);
            *reinterpret_cast<unsigned int*>(&hb[(q * 4 + i) * HBP + dwi]) = pk;
        }
        // rotate prefetch
#pragma unroll
        for (int nt = 0; nt < 4; ++nt) ca[nt] = na[nt];
#pragma unroll
        for (int nt = 0; nt < 2; ++nt) cxh[nt] = nxh[nt];
        BARRIER_LGKM();
    }

    // ---- write h_last ----
#pragma unroll
    for (int nt = 0; nt < 2; ++nt)
#pragma unroll
        for (int i = 0; i < 4; ++i)
            out[(size_t)(g * 16 + q * 4 + i) * 256 + w * 32 + nt * 16 + c16] = hreg[nt][i];
}

extern "C" void kernel_launch(void* const* d_in, const int* in_sizes, int n_in,
                              void* d_out, int out_size, void* d_ws, size_t ws_size,
                              hipStream_t stream) {
    const float* x   = (const float*)d_in[0];
    const float* Wzr = (const float*)d_in[1];
    const float* Uzr = (const float*)d_in[2];
    const float* bzr = (const float*)d_in[3];
    const float* Wh  = (const float*)d_in[4];
    const float* Uh  = (const float*)d_in[5];
    const float* bh  = (const float*)d_in[6];
    float* out = (float*)d_out;

    // ws: Wt bf16 [768][256] = 393216 B, then xzh bf16 [T][8][768][16] = 201326592 B
    unsigned short* Wt  = (unsigned short*)d_ws;
    unsigned short* xzh = (unsigned short*)((char*)d_ws + 393216);

    wt_kernel<<<dim3(768), dim3(64), 0, stream>>>(Wzr, Wh, Wt);
    proj_kernel<<<dim3(2048), dim3(256), 0, stream>>>(x, Wt, bzr, bh, xzh);
    gru_rec<<<dim3(8), dim3(512), 0, stream>>>(Uzr, Uh, xzh, out);
}

// Round 7
// 2197.578 us; speedup vs baseline: 1.2934x; 1.2934x over previous
//
#include <hip/hip_runtime.h>
#include <hip/hip_bf16.h>
#include <cstdint>
#include <cstddef>

#define B_ 128
#define T_ 1024
#define D_ 256
#define U_ 256

typedef __bf16 bfrag __attribute__((ext_vector_type(8)));
typedef unsigned short us8 __attribute__((ext_vector_type(8)));
typedef unsigned short us4 __attribute__((ext_vector_type(4)));
typedef float f32x4 __attribute__((ext_vector_type(4)));

__device__ __forceinline__ unsigned short f2bf(float f) {
    unsigned int u = __builtin_bit_cast(unsigned int, f);
    unsigned int r = (u + 0x7fffu + ((u >> 16) & 1u)) >> 16;
    return (unsigned short)r;
}
__device__ __forceinline__ float bf2f(unsigned short h) {
    unsigned int u = ((unsigned int)h) << 16;
    return __builtin_bit_cast(float, u);
}
// HW packed f32->2xbf16 (RNE). Used ONLY in wt/proj (one-shot kernels);
// in gru_rec's hot loop inline asm perturbed scheduling (R3 regression).
__device__ __forceinline__ unsigned int pk_bf16(float lo, float hi) {
    unsigned int d;
    asm("v_cvt_pk_bf16_f32 %0, %1, %2" : "=v"(d) : "v"(lo), "v"(hi));
    return d;
}

#if __has_builtin(__builtin_amdgcn_exp2f)
__device__ __forceinline__ float fexp2(float x) { return __builtin_amdgcn_exp2f(x); }
#else
__device__ __forceinline__ float fexp2(float x) { return exp2f(x); }
#endif
#if __has_builtin(__builtin_amdgcn_rcpf)
__device__ __forceinline__ float frcp(float x) { return __builtin_amdgcn_rcpf(x); }
#else
__device__ __forceinline__ float frcp(float x) { return 1.0f / x; }
#endif

__device__ __forceinline__ float sigm(float x) {
    return frcp(1.0f + fexp2(-1.4426950408889634f * x));
}
__device__ __forceinline__ float tanh_(float x) {
    return 1.0f - 2.0f * frcp(1.0f + fexp2(2.8853900817779268f * x));
}

// lgkm-only barrier: LDS writes visible, in-flight global loads NOT drained
#define BARRIER_LGKM() asm volatile("s_waitcnt lgkmcnt(0)\n\ts_barrier" ::: "memory")

// xzh layout: [t][g(8)][col(768)][b_local(16)] bf16. col<512: xz+b_zr; col>=512: xh+b_h
#define TSTR (8 * 768 * 16)   // shorts per timestep
#define WTSZ (768 * 256)      // shorts per Wt copy

// ---------------------------------------------------------------------------
// wt_kernel: Wt[col(768)][k(256)] bf16 = transpose of [W_zr | W_h],
// replicated `ncopies` times so concurrent proj blocks hit disjoint L2 lines.
// ---------------------------------------------------------------------------
__global__ __launch_bounds__(64) void wt_kernel(
    const float* __restrict__ Wzr, const float* __restrict__ Wh,
    unsigned short* __restrict__ Wt, int ncopies)
{
    const int c = blockIdx.x;      // 0..767
    const int lane = threadIdx.x;  // 0..63
    const float* Wp; int ldw, cc;
    if (c < 512) { Wp = Wzr; ldw = 512; cc = c; }
    else         { Wp = Wh;  ldw = 256; cc = c - 512; }
    const int k0 = lane * 4;
    const float a = Wp[(size_t)(k0 + 0) * ldw + cc];
    const float b = Wp[(size_t)(k0 + 1) * ldw + cc];
    const float d = Wp[(size_t)(k0 + 2) * ldw + cc];
    const float e = Wp[(size_t)(k0 + 3) * ldw + cc];
    uint2 u; u.x = pk_bf16(a, b); u.y = pk_bf16(d, e);
    for (int r = 0; r < ncopies; ++r)
        *reinterpret_cast<uint2*>(&Wt[(size_t)r * WTSZ + (size_t)c * 256 + k0]) = u;
}

// ---------------------------------------------------------------------------
// proj: xzh = x @ [W_zr | W_h] + bias, bf16 out.
// Block 256 thr / 4 waves, BM=64 (16 b x 4 t), N=768 in 12 chunks of 64,
// K=256. A staged to LDS coalesced; A-frags in regs. W read directly from
// L2-resident Wt (per-bb replica when available) via per-lane b128 loads in
// exact MFMA B-fragment layout. 4 blocks/CU for latency hiding.
// ---------------------------------------------------------------------------
#define LPA 264  // ldsA row pad (shorts): 528 B rows, 16-B aligned

__global__ __launch_bounds__(256, 4) void proj_kernel(
    const float* __restrict__ x, const unsigned short* __restrict__ Wt,
    const float* __restrict__ bzr, const float* __restrict__ bh,
    unsigned short* __restrict__ xzh, size_t wtstride)
{
    const int tid  = threadIdx.x;
    const int lane = tid & 63;
    const int wv   = tid >> 6;
    const int q    = lane >> 4;
    const int c16  = lane & 15;
    const int bb = blockIdx.x >> 8;   // batch block (16 b)
    const int tb = blockIdx.x & 255;  // time block (4 t)

    __shared__ __align__(16) unsigned short ldsA[64 * LPA];

    // ---- stage A (64 rows x 256 k), coalesced: one full row per instr ----
    {
        const int r0 = wv * 16;
#pragma unroll
        for (int r = 0; r < 16; ++r) {
            const int row = r0 + r;
            const float* xr = x + (((size_t)(bb * 16 + (row & 15))) * T_
                                   + tb * 4 + (row >> 4)) * D_;
            f32x4 v = *reinterpret_cast<const f32x4*>(xr + lane * 4);
            uint2 u; u.x = pk_bf16(v[0], v[1]); u.y = pk_bf16(v[2], v[3]);
            *reinterpret_cast<uint2*>(&ldsA[row * LPA + lane * 4]) = u;
        }
    }
    __syncthreads();

    // ---- A fragments to regs: rows (wv>>1)*32 + m2*16 + c16 ----
    const int R0 = (wv >> 1) * 32;
    us8 af[2][8];
#pragma unroll
    for (int m2 = 0; m2 < 2; ++m2)
#pragma unroll
        for (int kk = 0; kk < 8; ++kk)
            af[m2][kk] = *reinterpret_cast<const us8*>(
                &ldsA[(R0 + m2 * 16 + c16) * LPA + kk * 32 + q * 8]);

    const int wn = wv & 1;
    const unsigned short* p0 = Wt + (size_t)bb * wtstride
                               + ((size_t)(wn * 32 + c16) * 256 + q * 8);
    const unsigned short* p1 = p0 + 16 * 256;

#pragma unroll 1
    for (int ch = 0; ch < 12; ++ch) {
        f32x4 acc[2][2] = {};
#pragma unroll
        for (int kk = 0; kk < 8; ++kk) {
            us8 w0 = *reinterpret_cast<const us8*>(p0 + kk * 32);
            us8 w1 = *reinterpret_cast<const us8*>(p1 + kk * 32);
#pragma unroll
            for (int m2 = 0; m2 < 2; ++m2) {
                acc[m2][0] = __builtin_amdgcn_mfma_f32_16x16x32_bf16(
                    __builtin_bit_cast(bfrag, af[m2][kk]), __builtin_bit_cast(bfrag, w0),
                    acc[m2][0], 0, 0, 0);
                acc[m2][1] = __builtin_amdgcn_mfma_f32_16x16x32_bf16(
                    __builtin_bit_cast(bfrag, af[m2][kk]), __builtin_bit_cast(bfrag, w1),
                    acc[m2][1], 0, 0, 0);
            }
        }
#pragma unroll
        for (int n2 = 0; n2 < 2; ++n2) {
            const int gcn = ch * 64 + wn * 32 + n2 * 16 + c16;
            const float bias = (gcn < 512) ? bzr[gcn] : bh[gcn - 512];
#pragma unroll
            for (int m2 = 0; m2 < 2; ++m2) {
                const int t = tb * 4 + (wv >> 1) * 2 + m2;
                uint2 uu;
                uu.x = pk_bf16(acc[m2][n2][0] + bias, acc[m2][n2][1] + bias);
                uu.y = pk_bf16(acc[m2][n2][2] + bias, acc[m2][n2][3] + bias);
                *reinterpret_cast<uint2*>(
                    &xzh[(((size_t)t * 8 + bb) * 768 + gcn) * 16 + q * 4]) = uu;
            }
        }
        p0 += 64 * 256; p1 += 64 * 256;
    }
}

// ---------------------------------------------------------------------------
// gru_rec: R4 body (proven 1870 us) with ONE change: the Z-gate sigmoids are
// moved past BARRIER1, textually after the phase-B MFMA loop. Their inputs
// (acc[0..1]) are ready at the barrier; their result (zreg) is needed only at
// the h-update. Placing them in the phase-B region lets their transcendental
// issue overlap the matrix-pipe drain of the phase-B MFMAs — overlap the
// compiler cannot create itself across the asm barrier.
// ---------------------------------------------------------------------------
#define HBP 264  // shorts per row

__global__ __launch_bounds__(512, 2) void gru_rec(
    const float* __restrict__ Uzr, const float* __restrict__ Uh,
    const unsigned short* __restrict__ xzh, float* __restrict__ out)
{
    const int tid  = threadIdx.x;
    const int lane = tid & 63;
    const int w    = tid >> 6;
    const int q    = lane >> 4;
    const int c16  = lane & 15;
    const int g    = blockIdx.x;

    __shared__ __align__(16) unsigned short hb[16 * HBP];
    __shared__ __align__(16) unsigned short rhb[16 * HBP];

    // weight preload, k-perm: position p=kk*32+q*8+j holds h-row
    // kr = kk*32 + q*4 + (j>>1) + 16*(j&1)
    us8 wA[4][8];
#pragma unroll
    for (int nt = 0; nt < 4; ++nt) {
        const int col = (nt < 2) ? (w * 32 + nt * 16 + c16)
                                 : (256 + w * 32 + (nt - 2) * 16 + c16);
#pragma unroll
        for (int kk = 0; kk < 8; ++kk) {
            us8 v;
#pragma unroll
            for (int j = 0; j < 8; ++j) {
                const int kr = kk * 32 + q * 4 + (j >> 1) + 16 * (j & 1);
                v[j] = f2bf(Uzr[(size_t)kr * 512 + col]);
            }
            wA[nt][kk] = v;
        }
    }
    us8 wB[2][8];
#pragma unroll
    for (int nt = 0; nt < 2; ++nt) {
        const int col = w * 32 + nt * 16 + c16;
#pragma unroll
        for (int kk = 0; kk < 8; ++kk) {
            us8 v;
#pragma unroll
            for (int j = 0; j < 8; ++j) {
                const int kr = kk * 32 + q * 4 + (j >> 1) + 16 * (j & 1);
                v[j] = f2bf(Uh[(size_t)kr * 256 + col]);
            }
            wB[nt][kk] = v;
        }
    }

    for (int i = tid; i < 16 * HBP; i += 512) { hb[i] = 0; rhb[i] = 0; }
    __syncthreads();

    float hreg[2][4] = {{0, 0, 0, 0}, {0, 0, 0, 0}};

    // per-lane xzh base offsets (shorts)
    size_t laneA[4], laneB[2];
#pragma unroll
    for (int nt = 0; nt < 4; ++nt) {
        const int col = (nt < 2) ? (w * 32 + nt * 16 + c16)
                                 : (256 + w * 32 + (nt - 2) * 16 + c16);
        laneA[nt] = ((size_t)g * 768 + col) * 16 + q * 4;
    }
#pragma unroll
    for (int nt = 0; nt < 2; ++nt)
        laneB[nt] = ((size_t)g * 768 + 512 + w * 32 + nt * 16 + c16) * 16 + q * 4;

    // prefetch t=0
    us4 ca[4], cxh[2];
#pragma unroll
    for (int nt = 0; nt < 4; ++nt)
        ca[nt] = *reinterpret_cast<const us4*>(&xzh[laneA[nt]]);
#pragma unroll
    for (int nt = 0; nt < 2; ++nt)
        cxh[nt] = *reinterpret_cast<const us4*>(&xzh[laneB[nt]]);

    size_t toff = TSTR;  // points at t+1 data

    const int dwi = w * 32 + 2 * c16;  // packed-dword short index within row

#pragma unroll 1
    for (int t = 0; t < T_; ++t) {
        // issue next step's prefetch (lands any time before end of step)
        us4 na[4], nxh[2];
#pragma unroll
        for (int nt = 0; nt < 4; ++nt)
            na[nt] = *reinterpret_cast<const us4*>(&xzh[laneA[nt] + toff]);
#pragma unroll
        for (int nt = 0; nt < 2; ++nt)
            nxh[nt] = *reinterpret_cast<const us4*>(&xzh[laneB[nt] + toff]);
        if (t < 1022) toff += TSTR;

        // ---- phase A: z = xz + h @ U_zr ----
        f32x4 acc[4];
#pragma unroll
        for (int nt = 0; nt < 4; ++nt) {
            acc[nt][0] = bf2f(ca[nt][0]); acc[nt][1] = bf2f(ca[nt][1]);
            acc[nt][2] = bf2f(ca[nt][2]); acc[nt][3] = bf2f(ca[nt][3]);
        }
#pragma unroll
        for (int kk = 0; kk < 8; ++kk) {
            bfrag af = __builtin_bit_cast(bfrag,
                *reinterpret_cast<const us8*>(&hb[c16 * HBP + kk * 32 + q * 8]));
#pragma unroll
            for (int nt = 0; nt < 4; ++nt)
                acc[nt] = __builtin_amdgcn_mfma_f32_16x16x32_bf16(
                    af, __builtin_bit_cast(bfrag, wA[nt][kk]), acc[nt], 0, 0, 0);
        }
        // R -> R*h -> rhb (packed dword). Z-sigmoids DEFERRED past barrier.
#pragma unroll
        for (int i = 0; i < 4; ++i) {
            const float r0 = sigm(acc[2][i]);
            const float r1 = sigm(acc[3][i]);
            const unsigned int pk = (unsigned int)f2bf(r0 * hreg[0][i]) |
                                    ((unsigned int)f2bf(r1 * hreg[1][i]) << 16);
            *reinterpret_cast<unsigned int*>(&rhb[(q * 4 + i) * HBP + dwi]) = pk;
        }
        BARRIER_LGKM();

        // ---- phase B: s = tanh(xh + (R*h) @ U_h); h update ----
        f32x4 acc2[2];
#pragma unroll
        for (int nt = 0; nt < 2; ++nt) {
            acc2[nt][0] = bf2f(cxh[nt][0]); acc2[nt][1] = bf2f(cxh[nt][1]);
            acc2[nt][2] = bf2f(cxh[nt][2]); acc2[nt][3] = bf2f(cxh[nt][3]);
        }
#pragma unroll
        for (int kk = 0; kk < 8; ++kk) {
            bfrag rf = __builtin_bit_cast(bfrag,
                *reinterpret_cast<const us8*>(&rhb[c16 * HBP + kk * 32 + q * 8]));
#pragma unroll
            for (int nt = 0; nt < 2; ++nt)
                acc2[nt] = __builtin_amdgcn_mfma_f32_16x16x32_bf16(
                    rf, __builtin_bit_cast(bfrag, wB[nt][kk]), acc2[nt], 0, 0, 0);
        }
        // Z-sigmoids here: inputs ready since phase A; issue overlaps the
        // matrix-pipe drain of the phase-B MFMAs above.
        float zreg[2][4];
#pragma unroll
        for (int i = 0; i < 4; ++i) {
            zreg[0][i] = sigm(acc[0][i]);
            zreg[1][i] = sigm(acc[1][i]);
        }
#pragma unroll
        for (int i = 0; i < 4; ++i) {
            const float s0 = tanh_(acc2[0][i]);
            const float s1 = tanh_(acc2[1][i]);
            const float h0 = hreg[0][i] + zreg[0][i] * (s0 - hreg[0][i]);
            const float h1 = hreg[1][i] + zreg[1][i] * (s1 - hreg[1][i]);
            hreg[0][i] = h0; hreg[1][i] = h1;
            const unsigned int pk = (unsigned int)f2bf(h0) |
                                    ((unsigned int)f2bf(h1) << 16);
            *reinterpret_cast<unsigned int*>(&hb[(q * 4 + i) * HBP + dwi]) = pk;
        }
        // rotate prefetch
#pragma unroll
        for (int nt = 0; nt < 4; ++nt) ca[nt] = na[nt];
#pragma unroll
        for (int nt = 0; nt < 2; ++nt) cxh[nt] = nxh[nt];
        BARRIER_LGKM();
    }

    // ---- write h_last ----
#pragma unroll
    for (int nt = 0; nt < 2; ++nt)
#pragma unroll
        for (int i = 0; i < 4; ++i)
            out[(size_t)(g * 16 + q * 4 + i) * 256 + w * 32 + nt * 16 + c16] = hreg[nt][i];
}

extern "C" void kernel_launch(void* const* d_in, const int* in_sizes, int n_in,
                              void* d_out, int out_size, void* d_ws, size_t ws_size,
                              hipStream_t stream) {
    const float* x   = (const float*)d_in[0];
    const float* Wzr = (const float*)d_in[1];
    const float* Uzr = (const float*)d_in[2];
    const float* bzr = (const float*)d_in[3];
    const float* Wh  = (const float*)d_in[4];
    const float* Uh  = (const float*)d_in[5];
    const float* bh  = (const float*)d_in[6];
    float* out = (float*)d_out;

    // ws layout: [xzh 201326592 B][Wt replicas]. xzh at offset 0 (footprint
    // proven R2-R5); replication engages only if ws_size covers the tail.
    const size_t xzhbytes = (size_t)T_ * TSTR * 2;   // 201326592
    const size_t wtbytes  = (size_t)WTSZ * 2;        // 393216 per copy
    int ncopies = (ws_size >= xzhbytes + 8 * wtbytes) ? 8
                : (ws_size >= xzhbytes + wtbytes) ? 1 : 1;
    unsigned short* xzh = (unsigned short*)d_ws;
    unsigned short* Wt  = (unsigned short*)((char*)d_ws + xzhbytes);
    const size_t wtstride = (ncopies == 8) ? (size_t)WTSZ : 0;  // shorts per bb replica

    wt_kernel<<<dim3(768), dim3(64), 0, stream>>>(Wzr, Wh, Wt, ncopies);
    proj_kernel<<<dim3(2048), dim3(256), 0, stream>>>(x, Wt, bzr, bh, xzh, wtstride);
    gru_rec<<<dim3(8), dim3(512), 0, stream>>>(Uzr, Uh, xzh, out);
}